// Round 1
// baseline (690.658 us; speedup 1.0000x reference)
//
#include <hip/hip_runtime.h>

// BitNetAttention on MI355X (gfx950).
// S=2048 B=4 E=1024 H=16 HD=64.  d_out = [ out (S*B*E f32) | attn_weights (B*S*S f32) ].
// Workspace requirement: ~138 MB (see offsets below).
//
// Accuracy strategy: ternary weights are exact in bf16; activations are hi/lo
// bf16 split so MFMA products carry ~f32 accuracy where the 2^-9 threshold needs it
// (QKV projection inputs, Q/K into scores). P/V/attn are single bf16 (error there is
// damped by softmax normalization and the small w_scale).

typedef __bf16 bf16_t;
typedef __bf16 bf16x8 __attribute__((ext_vector_type(8)));
typedef float  f32x4  __attribute__((ext_vector_type(4)));

#define MFMA16(Af, Bf, Cv) __builtin_amdgcn_mfma_f32_16x16x32_bf16((Af), (Bf), (Cv), 0, 0, 0)

__device__ __forceinline__ void gload16(const void* g, void* l) {
  __builtin_amdgcn_global_load_lds(
      (const __attribute__((address_space(1))) void*)g,
      (__attribute__((address_space(3))) void*)l, 16, 0, 0);
}

// ---------------- constants ----------------
constexpr int S_ = 2048, B_ = 4, E_ = 1024, H_ = 16, HD_ = 64;
constexpr int M_ = S_ * B_;        // 8192
constexpr int NH_ = B_ * H_;       // 64 heads

// workspace offsets (bytes)
constexpr size_t OFF_SCALES = 0;                         // 8 f32: wq,wk,wv,wo,a_x,a_attn
constexpr size_t OFF_PART   = 256;                       // 6*256 f32 partials
constexpr size_t OFF_XH     = 8192;
constexpr size_t SZ_X       = (size_t)M_ * E_ * 2;       // 16 MB
constexpr size_t OFF_XL     = OFF_XH + SZ_X;
constexpr size_t OFF_TQKV   = OFF_XL + SZ_X;             // ternary [3072][1024] bf16
constexpr size_t OFF_TO     = OFF_TQKV + (size_t)3072 * 1024 * 2;
constexpr size_t OFF_QH     = OFF_TO + (size_t)1024 * 1024 * 2;
constexpr size_t SZ_HD      = (size_t)NH_ * S_ * HD_ * 2;  // 16 MB
constexpr size_t OFF_QL     = OFF_QH + SZ_HD;
constexpr size_t OFF_KH     = OFF_QL + SZ_HD;
constexpr size_t OFF_KL     = OFF_KH + SZ_HD;
constexpr size_t OFF_VB     = OFF_KL + SZ_HD;
constexpr size_t OFF_STM    = OFF_VB + SZ_HD;            // [64][2048] f32
constexpr size_t OFF_STL    = OFF_STM + (size_t)NH_ * S_ * 4;
constexpr size_t OFF_ATTN   = OFF_STL + (size_t)NH_ * S_ * 4;  // bf16 [8192][1024]
// end = OFF_ATTN + 16MB ~= 137 MB

// ---------------- reductions for scales ----------------
__global__ void k_abs_sum_f32(const float4* __restrict__ src, int n4, float* __restrict__ out) {
  float s = 0.f;
  for (int i = blockIdx.x * blockDim.x + threadIdx.x; i < n4; i += gridDim.x * blockDim.x) {
    float4 x = src[i];
    s += fabsf(x.x) + fabsf(x.y) + fabsf(x.z) + fabsf(x.w);
  }
  __shared__ float red[256];
  red[threadIdx.x] = s; __syncthreads();
  for (int st = 128; st > 0; st >>= 1) {
    if (threadIdx.x < st) red[threadIdx.x] += red[threadIdx.x + st];
    __syncthreads();
  }
  if (threadIdx.x == 0) out[blockIdx.x] = red[0];
}

__global__ void k_abs_sum_bf16(const bf16x8* __restrict__ src, int n8, float* __restrict__ out) {
  float s = 0.f;
  for (int i = blockIdx.x * blockDim.x + threadIdx.x; i < n8; i += gridDim.x * blockDim.x) {
    bf16x8 x = src[i];
    #pragma unroll
    for (int e = 0; e < 8; ++e) s += fabsf((float)x[e]);
  }
  __shared__ float red[256];
  red[threadIdx.x] = s; __syncthreads();
  for (int st = 128; st > 0; st >>= 1) {
    if (threadIdx.x < st) red[threadIdx.x] += red[threadIdx.x + st];
    __syncthreads();
  }
  if (threadIdx.x == 0) out[blockIdx.x] = red[0];
}

__global__ void k_finalize(const float* __restrict__ part, float* __restrict__ scales,
                           int r0, int r1) {
  __shared__ float red[256];
  int t = threadIdx.x;
  for (int r = r0; r < r1; ++r) {
    red[t] = part[r * 256 + t];
    __syncthreads();
    for (int st = 128; st > 0; st >>= 1) {
      if (t < st) red[t] += red[t + st];
      __syncthreads();
    }
    if (t == 0) {
      float cnt = (r < 4) ? 1048576.0f : 8388608.0f;
      scales[r] = fmaxf(red[0] / cnt, 1e-8f);
    }
    __syncthreads();
  }
}

// ---------------- quantize / split ----------------
__device__ __forceinline__ unsigned short tern_u(float w, float wsc) {
  float wn = w / wsc;                                   // match reference: divide, then compare
  if (!(fabsf(wn) > 0.5f)) return 0;
  return (wn > 0.f) ? (unsigned short)0x3F80 : (unsigned short)0xBF80;  // +-1.0 bf16
}

__global__ void k_quantize(const float4* __restrict__ W, const float* __restrict__ scales,
                           int seg, ushort4* __restrict__ T) {
  int i = blockIdx.x * 256 + threadIdx.x;   // 1024 blocks -> exactly 1M elems
  float wsc = scales[seg];
  float4 w = W[i];
  ushort4 o;
  o.x = tern_u(w.x, wsc); o.y = tern_u(w.y, wsc);
  o.z = tern_u(w.z, wsc); o.w = tern_u(w.w, wsc);
  T[i] = o;
}

__device__ __forceinline__ void split1(float v, unsigned short& h, unsigned short& l) {
  __bf16 hb = (__bf16)v;
  __bf16 lb = (__bf16)(v - (float)hb);
  h = __builtin_bit_cast(unsigned short, hb);
  l = __builtin_bit_cast(unsigned short, lb);
}

__global__ void k_split_x(const float4* __restrict__ X, ushort4* __restrict__ Xh,
                          ushort4* __restrict__ Xl) {
  int i = blockIdx.x * 256 + threadIdx.x;   // 8192 blocks -> exactly 8.4M elems
  float4 v = X[i];
  ushort4 h, l;
  split1(v.x, h.x, l.x); split1(v.y, h.y, l.y);
  split1(v.z, h.z, l.z); split1(v.w, h.w, l.w);
  Xh[i] = h; Xl[i] = l;
}

// ---------------- QKV projection GEMM ----------------
// C[m, n] = (Xh+Xl)[m, :] . T[n, :]  (B^T form), m in [0,8192), n in [0,3072)
// 128x128 tile, 4 waves 2x2, K-step 64, global_load_lds staging (m97 structure).
__global__ __launch_bounds__(256) void k_gemm_qkv(
    const bf16_t* __restrict__ Xh, const bf16_t* __restrict__ Xl,
    const bf16_t* __restrict__ T, const float* __restrict__ scales,
    const float* __restrict__ bq, const float* __restrict__ bk, const float* __restrict__ bv,
    bf16_t* __restrict__ Qh, bf16_t* __restrict__ Ql,
    bf16_t* __restrict__ Kh, bf16_t* __restrict__ Kl, bf16_t* __restrict__ Vb) {
  __shared__ bf16_t Ah[128 * 64], Al[128 * 64], Bs[128 * 64];
  const int tid = threadIdx.x, w = tid >> 6, lane = tid & 63;
  const int g = lane >> 4, cc = lane & 15;
  const int bm = blockIdx.x * 128, bn = blockIdx.y * 128;
  const int wm = (w >> 1) * 64, wn = (w & 1) * 64;
  const int srow = lane >> 3, scol = (lane & 7) * 8;
  f32x4 acc[4][4] = {};
  for (int kt = 0; kt < 16; ++kt) {
    const int k0 = kt * 64;
    #pragma unroll
    for (int c = 0; c < 4; ++c) {
      int chunk = w * 4 + c;
      int row = chunk * 8 + srow;
      gload16(&Xh[(bm + row) * 1024 + k0 + scol], (char*)Ah + chunk * 1024);
      gload16(&Xl[(bm + row) * 1024 + k0 + scol], (char*)Al + chunk * 1024);
      gload16(&T[(bn + row) * 1024 + k0 + scol], (char*)Bs + chunk * 1024);
    }
    __syncthreads();
    #pragma unroll
    for (int ks = 0; ks < 2; ++ks) {
      bf16x8 af[4], lf[4], bfr[4];
      #pragma unroll
      for (int i = 0; i < 4; ++i)
        af[i] = *(const bf16x8*)&Ah[(wm + i * 16 + cc) * 64 + ks * 32 + g * 8];
      #pragma unroll
      for (int i = 0; i < 4; ++i)
        lf[i] = *(const bf16x8*)&Al[(wm + i * 16 + cc) * 64 + ks * 32 + g * 8];
      #pragma unroll
      for (int j = 0; j < 4; ++j)
        bfr[j] = *(const bf16x8*)&Bs[(wn + j * 16 + cc) * 64 + ks * 32 + g * 8];
      #pragma unroll
      for (int i = 0; i < 4; ++i)
        #pragma unroll
        for (int j = 0; j < 4; ++j) {
          acc[i][j] = MFMA16(af[i], bfr[j], acc[i][j]);
          acc[i][j] = MFMA16(lf[i], bfr[j], acc[i][j]);
        }
    }
    __syncthreads();
  }
  // epilogue: scale, bias, fold 1/sqrt(HD) into q, hi/lo split, scatter to head layout
  const int seg = bn >> 10;   // 0=q 1=k 2=v (uniform per block)
  const float wsc = scales[seg];
  const float asx = scales[4];
  const float* bias = (seg == 0) ? bq : (seg == 1) ? bk : bv;
  #pragma unroll
  for (int i = 0; i < 4; ++i)
    #pragma unroll
    for (int j = 0; j < 4; ++j)
      #pragma unroll
      for (int r = 0; r < 4; ++r) {
        int m = bm + wm + i * 16 + g * 4 + r;
        int n = bn + wn + j * 16 + cc;
        int e = n & 1023;
        float v = acc[i][j][r] * wsc + bias[e] * asx;
        int s = m >> 2, b = m & 3, h = e >> 6, d = e & 63;
        int idx = ((b * 16 + h) * 2048 + s) * 64 + d;
        if (seg == 0) {
          v *= 0.125f;   // HD^-0.5, exact
          __bf16 hb = (__bf16)v; __bf16 lb = (__bf16)(v - (float)hb);
          Qh[idx] = hb; Ql[idx] = lb;
        } else if (seg == 1) {
          __bf16 hb = (__bf16)v; __bf16 lb = (__bf16)(v - (float)hb);
          Kh[idx] = hb; Kl[idx] = lb;
        } else {
          Vb[idx] = (__bf16)v;
        }
      }
}

// ---------------- flash attention (per head x 64-q-tile) ----------------
// online softmax; 3-split QK^T; P,V single bf16; writes attn (bf16) + per-row (m,l) stats.
__global__ __launch_bounds__(256) void k_flash(
    const bf16_t* __restrict__ Qh, const bf16_t* __restrict__ Ql,
    const bf16_t* __restrict__ Kh, const bf16_t* __restrict__ Kl,
    const bf16_t* __restrict__ Vb,
    bf16_t* __restrict__ attnb, float* __restrict__ stm, float* __restrict__ stl) {
  __shared__ bf16_t Khs[64 * 72], Kls[64 * 72], VT[64 * 72], Ps[64 * 72];  // +8 pad rows
  const int tid = threadIdx.x, w = tid >> 6, lane = tid & 63;
  const int g = lane >> 4, cc = lane & 15;
  const int head = blockIdx.y, q0 = blockIdx.x * 64;
  const int qbase = (head * 2048 + q0 + w * 16 + cc) * 64 + g * 8;
  const bf16x8 qh0 = *(const bf16x8*)&Qh[qbase];
  const bf16x8 qh1 = *(const bf16x8*)&Qh[qbase + 32];
  const bf16x8 ql0 = *(const bf16x8*)&Ql[qbase];
  const bf16x8 ql1 = *(const bf16x8*)&Ql[qbase + 32];
  float m_[4], l_[4];
  f32x4 accO[4] = {};
  #pragma unroll
  for (int r = 0; r < 4; ++r) { m_[r] = -1e30f; l_[r] = 0.f; }
  const int srow = tid >> 2, scol = (tid & 3) * 16;
  for (int kt0 = 0; kt0 < 2048; kt0 += 64) {
    {  // stage K hi/lo (row-major, padded) + V transposed
      const int gb = (head * 2048 + kt0 + srow) * 64 + scol;
      bf16x8 a0 = *(const bf16x8*)&Kh[gb];
      bf16x8 a1 = *(const bf16x8*)&Kh[gb + 8];
      bf16x8 c0 = *(const bf16x8*)&Kl[gb];
      bf16x8 c1 = *(const bf16x8*)&Kl[gb + 8];
      bf16x8 v0 = *(const bf16x8*)&Vb[gb];
      bf16x8 v1 = *(const bf16x8*)&Vb[gb + 8];
      *(bf16x8*)&Khs[srow * 72 + scol] = a0;
      *(bf16x8*)&Khs[srow * 72 + scol + 8] = a1;
      *(bf16x8*)&Kls[srow * 72 + scol] = c0;
      *(bf16x8*)&Kls[srow * 72 + scol + 8] = c1;
      #pragma unroll
      for (int e = 0; e < 8; ++e) {
        VT[(scol + e) * 72 + srow] = v0[e];
        VT[(scol + 8 + e) * 72 + srow] = v1[e];
      }
    }
    __syncthreads();
    // S = Q.K^T (3-split)
    f32x4 sacc[4] = {};
    #pragma unroll
    for (int nf = 0; nf < 4; ++nf) {
      #pragma unroll
      for (int ks = 0; ks < 2; ++ks) {
        bf16x8 kh = *(const bf16x8*)&Khs[(nf * 16 + cc) * 72 + ks * 32 + g * 8];
        bf16x8 kl = *(const bf16x8*)&Kls[(nf * 16 + cc) * 72 + ks * 32 + g * 8];
        const bf16x8 qhf = ks ? qh1 : qh0;
        const bf16x8 qlf = ks ? ql1 : ql0;
        sacc[nf] = MFMA16(qhf, kh, sacc[nf]);
        sacc[nf] = MFMA16(qlf, kh, sacc[nf]);
        sacc[nf] = MFMA16(qhf, kl, sacc[nf]);
      }
    }
    // online softmax update (rows = g*4+r, cols across lanes 0..15 of each group)
    float tm[4];
    #pragma unroll
    for (int r = 0; r < 4; ++r)
      tm[r] = fmaxf(fmaxf(sacc[0][r], sacc[1][r]), fmaxf(sacc[2][r], sacc[3][r]));
    #pragma unroll
    for (int off = 1; off < 16; off <<= 1)
      #pragma unroll
      for (int r = 0; r < 4; ++r) tm[r] = fmaxf(tm[r], __shfl_xor(tm[r], off));
    float sc_[4], rs[4];
    #pragma unroll
    for (int r = 0; r < 4; ++r) {
      float mn = fmaxf(m_[r], tm[r]);
      sc_[r] = __expf(m_[r] - mn);
      m_[r] = mn;
      rs[r] = 0.f;
    }
    #pragma unroll
    for (int nf = 0; nf < 4; ++nf)
      #pragma unroll
      for (int r = 0; r < 4; ++r) {
        float p = __expf(sacc[nf][r] - m_[r]);
        rs[r] += p;
        Ps[(w * 16 + g * 4 + r) * 72 + nf * 16 + cc] = (bf16_t)p;  // wave-private rows
      }
    #pragma unroll
    for (int off = 1; off < 16; off <<= 1)
      #pragma unroll
      for (int r = 0; r < 4; ++r) rs[r] += __shfl_xor(rs[r], off);
    #pragma unroll
    for (int r = 0; r < 4; ++r) l_[r] = l_[r] * sc_[r] + rs[r];
    #pragma unroll
    for (int df = 0; df < 4; ++df)
      #pragma unroll
      for (int r = 0; r < 4; ++r) accO[df][r] *= sc_[r];
    // PV (P and V single bf16)
    const bf16x8 pa0 = *(const bf16x8*)&Ps[(w * 16 + cc) * 72 + g * 8];
    const bf16x8 pa1 = *(const bf16x8*)&Ps[(w * 16 + cc) * 72 + 32 + g * 8];
    #pragma unroll
    for (int df = 0; df < 4; ++df) {
      bf16x8 v0 = *(const bf16x8*)&VT[(df * 16 + cc) * 72 + g * 8];
      bf16x8 v1 = *(const bf16x8*)&VT[(df * 16 + cc) * 72 + 32 + g * 8];
      accO[df] = MFMA16(pa0, v0, accO[df]);
      accO[df] = MFMA16(pa1, v1, accO[df]);
    }
    __syncthreads();
  }
  // epilogue: normalize, write attn in [s,b,e] layout (bf16) + stats
  const int b = head >> 4, h = head & 15;
  #pragma unroll
  for (int df = 0; df < 4; ++df)
    #pragma unroll
    for (int r = 0; r < 4; ++r) {
      int q = q0 + w * 16 + g * 4 + r;
      int m = q * 4 + b;
      int e = h * 64 + df * 16 + cc;
      attnb[m * 1024 + e] = (bf16_t)(accO[df][r] / l_[r]);
    }
  if (cc == 0) {
    #pragma unroll
    for (int r = 0; r < 4; ++r) {
      int q = q0 + w * 16 + g * 4 + r;
      stm[head * 2048 + q] = m_[r];
      stl[head * 2048 + q] = l_[r];
    }
  }
}

// ---------------- head-mean probs (attn_weights) ----------------
// block = (q-tile 64, batch b, kt-chunk 256). Loops heads inner, accumulates
// mean-prob in registers, writes each attn_weights element exactly once.
__global__ __launch_bounds__(256) void k_pm(
    const bf16_t* __restrict__ Qh, const bf16_t* __restrict__ Ql,
    const bf16_t* __restrict__ Kh, const bf16_t* __restrict__ Kl,
    const float* __restrict__ stm, const float* __restrict__ stl,
    float* __restrict__ aw) {
  __shared__ bf16_t Khs[64 * 72], Kls[64 * 72];
  __shared__ float sm[1024], sl[1024];
  const int tid = threadIdx.x, w = tid >> 6, lane = tid & 63;
  const int g = lane >> 4, cc = lane & 15;
  const int q0 = blockIdx.x * 64;
  const int b = blockIdx.y;
  const int kbeg = blockIdx.z * 256;
  for (int i = tid; i < 1024; i += 256) {
    int h = i >> 6, q = i & 63;
    sm[i] = stm[(b * 16 + h) * 2048 + q0 + q];
    sl[i] = stl[(b * 16 + h) * 2048 + q0 + q];
  }
  const int srow = tid >> 2, scol = (tid & 3) * 16;
  for (int kt0 = kbeg; kt0 < kbeg + 256; kt0 += 64) {
    float pm[4][4] = {};
    for (int h = 0; h < 16; ++h) {
      const int head = b * 16 + h;
      __syncthreads();  // previous head's compute done before restage
      {
        const int gb = (head * 2048 + kt0 + srow) * 64 + scol;
        bf16x8 a0 = *(const bf16x8*)&Kh[gb];
        bf16x8 a1 = *(const bf16x8*)&Kh[gb + 8];
        bf16x8 c0 = *(const bf16x8*)&Kl[gb];
        bf16x8 c1 = *(const bf16x8*)&Kl[gb + 8];
        *(bf16x8*)&Khs[srow * 72 + scol] = a0;
        *(bf16x8*)&Khs[srow * 72 + scol + 8] = a1;
        *(bf16x8*)&Kls[srow * 72 + scol] = c0;
        *(bf16x8*)&Kls[srow * 72 + scol + 8] = c1;
      }
      __syncthreads();
      const int qbase = (head * 2048 + q0 + w * 16 + cc) * 64 + g * 8;
      bf16x8 qh0 = *(const bf16x8*)&Qh[qbase];
      bf16x8 qh1 = *(const bf16x8*)&Qh[qbase + 32];
      bf16x8 ql0 = *(const bf16x8*)&Ql[qbase];
      bf16x8 ql1 = *(const bf16x8*)&Ql[qbase + 32];
      f32x4 sacc[4] = {};
      #pragma unroll
      for (int nf = 0; nf < 4; ++nf) {
        #pragma unroll
        for (int ks = 0; ks < 2; ++ks) {
          bf16x8 kh = *(const bf16x8*)&Khs[(nf * 16 + cc) * 72 + ks * 32 + g * 8];
          bf16x8 kl = *(const bf16x8*)&Kls[(nf * 16 + cc) * 72 + ks * 32 + g * 8];
          bf16x8 qhf = ks ? qh1 : qh0;
          bf16x8 qlf = ks ? ql1 : ql0;
          sacc[nf] = MFMA16(qhf, kh, sacc[nf]);
          sacc[nf] = MFMA16(qlf, kh, sacc[nf]);
          sacc[nf] = MFMA16(qhf, kl, sacc[nf]);
        }
      }
      float mm[4], il[4];
      #pragma unroll
      for (int r = 0; r < 4; ++r) {
        int qloc = w * 16 + g * 4 + r;
        mm[r] = sm[h * 64 + qloc];
        il[r] = 1.f / sl[h * 64 + qloc];
      }
      #pragma unroll
      for (int nf = 0; nf < 4; ++nf)
        #pragma unroll
        for (int r = 0; r < 4; ++r)
          pm[nf][r] += __expf(sacc[nf][r] - mm[r]) * il[r];
    }
    #pragma unroll
    for (int nf = 0; nf < 4; ++nf)
      #pragma unroll
      for (int r = 0; r < 4; ++r) {
        int q = q0 + w * 16 + g * 4 + r;
        int k = kt0 + nf * 16 + cc;
        aw[((long)(b * 2048 + q)) * 2048 + k] = pm[nf][r] * 0.0625f;
      }
  }
}

// ---------------- output projection GEMM ----------------
__global__ __launch_bounds__(256) void k_gemm_out(
    const bf16_t* __restrict__ A, const bf16_t* __restrict__ T,
    const float* __restrict__ scales, const float* __restrict__ bo,
    float* __restrict__ out) {
  __shared__ bf16_t As[128 * 64], Bs2[128 * 64];
  const int tid = threadIdx.x, w = tid >> 6, lane = tid & 63;
  const int g = lane >> 4, cc = lane & 15;
  const int bm = blockIdx.x * 128, bn = blockIdx.y * 128;
  const int wm = (w >> 1) * 64, wn = (w & 1) * 64;
  const int srow = lane >> 3, scol = (lane & 7) * 8;
  f32x4 acc[4][4] = {};
  for (int kt = 0; kt < 16; ++kt) {
    const int k0 = kt * 64;
    #pragma unroll
    for (int c = 0; c < 4; ++c) {
      int chunk = w * 4 + c;
      int row = chunk * 8 + srow;
      gload16(&A[(bm + row) * 1024 + k0 + scol], (char*)As + chunk * 1024);
      gload16(&T[(bn + row) * 1024 + k0 + scol], (char*)Bs2 + chunk * 1024);
    }
    __syncthreads();
    #pragma unroll
    for (int ks = 0; ks < 2; ++ks) {
      bf16x8 af[4], bfr[4];
      #pragma unroll
      for (int i = 0; i < 4; ++i)
        af[i] = *(const bf16x8*)&As[(wm + i * 16 + cc) * 64 + ks * 32 + g * 8];
      #pragma unroll
      for (int j = 0; j < 4; ++j)
        bfr[j] = *(const bf16x8*)&Bs2[(wn + j * 16 + cc) * 64 + ks * 32 + g * 8];
      #pragma unroll
      for (int i = 0; i < 4; ++i)
        #pragma unroll
        for (int j = 0; j < 4; ++j)
          acc[i][j] = MFMA16(af[i], bfr[j], acc[i][j]);
    }
    __syncthreads();
  }
  const float wsc = scales[3], asa = scales[5];
  #pragma unroll
  for (int i = 0; i < 4; ++i)
    #pragma unroll
    for (int j = 0; j < 4; ++j)
      #pragma unroll
      for (int r = 0; r < 4; ++r) {
        int m = bm + wm + i * 16 + g * 4 + r;
        int n = bn + wn + j * 16 + cc;
        out[m * 1024 + n] = acc[i][j][r] * wsc + bo[n] * asa;
      }
}

// ---------------- host ----------------
extern "C" void kernel_launch(void* const* d_in, const int* in_sizes, int n_in,
                              void* d_out, int out_size, void* d_ws, size_t ws_size,
                              hipStream_t stream) {
  (void)in_sizes; (void)n_in; (void)out_size; (void)ws_size;  // needs ws_size >= ~138MB
  const float* query = (const float*)d_in[0];
  const float* Wq = (const float*)d_in[1];
  const float* bq = (const float*)d_in[2];
  const float* Wk = (const float*)d_in[3];
  const float* bk = (const float*)d_in[4];
  const float* Wv = (const float*)d_in[5];
  const float* bv = (const float*)d_in[6];
  const float* Wo = (const float*)d_in[7];
  const float* bo = (const float*)d_in[8];

  char* ws = (char*)d_ws;
  float*  scales = (float*)(ws + OFF_SCALES);
  float*  part   = (float*)(ws + OFF_PART);
  bf16_t* Xh     = (bf16_t*)(ws + OFF_XH);
  bf16_t* Xl     = (bf16_t*)(ws + OFF_XL);
  bf16_t* Tqkv   = (bf16_t*)(ws + OFF_TQKV);
  bf16_t* To     = (bf16_t*)(ws + OFF_TO);
  bf16_t* Qh     = (bf16_t*)(ws + OFF_QH);
  bf16_t* Ql     = (bf16_t*)(ws + OFF_QL);
  bf16_t* Kh     = (bf16_t*)(ws + OFF_KH);
  bf16_t* Kl     = (bf16_t*)(ws + OFF_KL);
  bf16_t* Vb     = (bf16_t*)(ws + OFF_VB);
  float*  Stm    = (float*)(ws + OFF_STM);
  float*  Stl    = (float*)(ws + OFF_STL);
  bf16_t* Attn   = (bf16_t*)(ws + OFF_ATTN);

  float* out0 = (float*)d_out;
  float* aw   = out0 + (size_t)M_ * E_;   // attn_weights region

  // scales: mean|W| x4, mean|query|
  k_abs_sum_f32<<<256, 256, 0, stream>>>((const float4*)Wq, 262144, part);
  k_abs_sum_f32<<<256, 256, 0, stream>>>((const float4*)Wk, 262144, part + 256);
  k_abs_sum_f32<<<256, 256, 0, stream>>>((const float4*)Wv, 262144, part + 512);
  k_abs_sum_f32<<<256, 256, 0, stream>>>((const float4*)Wo, 262144, part + 768);
  k_abs_sum_f32<<<256, 256, 0, stream>>>((const float4*)query, 2097152, part + 1024);
  k_finalize<<<1, 256, 0, stream>>>(part, scales, 0, 5);

  // ternary-quantize weights (exact bf16 {-1,0,1}), split x into hi/lo bf16
  k_quantize<<<1024, 256, 0, stream>>>((const float4*)Wq, scales, 0, (ushort4*)Tqkv);
  k_quantize<<<1024, 256, 0, stream>>>((const float4*)Wk, scales, 1, (ushort4*)(Tqkv + 1048576));
  k_quantize<<<1024, 256, 0, stream>>>((const float4*)Wv, scales, 2, (ushort4*)(Tqkv + 2097152));
  k_quantize<<<1024, 256, 0, stream>>>((const float4*)Wo, scales, 3, (ushort4*)To);
  k_split_x<<<8192, 256, 0, stream>>>((const float4*)query, (ushort4*)Xh, (ushort4*)Xl);

  // fused QKV projection -> Q(hi/lo, pre-scaled), K(hi/lo), V(bf16) in [head][s][d]
  k_gemm_qkv<<<dim3(64, 24), 256, 0, stream>>>(Xh, Xl, Tqkv, scales, bq, bk, bv,
                                               Qh, Ql, Kh, Kl, Vb);
  // flash attention + stats
  k_flash<<<dim3(32, 64), 256, 0, stream>>>(Qh, Ql, Kh, Kl, Vb, Attn, Stm, Stl);
  // head-averaged attention weights (deterministic, write-once)
  k_pm<<<dim3(32, 4, 8), 256, 0, stream>>>(Qh, Ql, Kh, Kl, Stm, Stl, aw);
  // a_scale for the output projection bias path
  k_abs_sum_bf16<<<256, 256, 0, stream>>>((const bf16x8*)Attn, 1048576, part + 1280);
  k_finalize<<<1, 256, 0, stream>>>(part, scales, 5, 6);
  // output projection
  k_gemm_out<<<dim3(64, 8), 256, 0, stream>>>(Attn, To, scales, bo, out0);
}